// Round 1
// baseline (3535.769 us; speedup 1.0000x reference)
//
#include <hip/hip_runtime.h>
#include <hip/hip_bf16.h>

#define NN 50000
#define NE 500000

typedef __hip_bfloat16 bf16;

__device__ __forceinline__ float wave_sum(float v) {
#pragma unroll
  for (int o = 32; o >= 1; o >>= 1) v += __shfl_xor(v, o);
  return v;
}

// ---------------- QKV: Qh/Kh/Vh = x @ W + b ----------------
__global__ __launch_bounds__(256) void qkv_kernel(
    const float* __restrict__ x,
    const float* __restrict__ Wq, const float* __restrict__ bq,
    const float* __restrict__ Wk, const float* __restrict__ bk,
    const float* __restrict__ Wv, const float* __restrict__ bv,
    float* __restrict__ Qh, float* __restrict__ Kh, float* __restrict__ Vh) {
  __shared__ float WqL[4096], WkL[4096], WvL[4096];
  __shared__ float bqL[64], bkL[64], bvL[64];
  const int tid = threadIdx.x;
  for (int i = tid; i < 4096; i += 256) { WqL[i] = Wq[i]; WkL[i] = Wk[i]; WvL[i] = Wv[i]; }
  if (tid < 64) { bqL[tid] = bq[tid]; bkL[tid] = bk[tid]; bvL[tid] = bv[tid]; }
  __syncthreads();
  const int lane = tid & 63;
  const int gw = blockIdx.x * 4 + (tid >> 6);
  const int stride = gridDim.x * 4 * 4;
  for (int nb = gw * 4; nb < NN; nb += stride) {
    float xr[4] = {0.f, 0.f, 0.f, 0.f};
#pragma unroll
    for (int j = 0; j < 4; j++)
      if (nb + j < NN) xr[j] = x[(size_t)(nb + j) * 64 + lane];
    float aq[4], ak[4], av[4];
#pragma unroll
    for (int j = 0; j < 4; j++) { aq[j] = bqL[lane]; ak[j] = bkL[lane]; av[j] = bvL[lane]; }
#pragma unroll
    for (int k = 0; k < 64; k++) {
      float rq = WqL[k * 64 + lane], rk = WkL[k * 64 + lane], rv = WvL[k * 64 + lane];
#pragma unroll
      for (int j = 0; j < 4; j++) {
        float w = __shfl(xr[j], k);
        aq[j] = fmaf(w, rq, aq[j]);
        ak[j] = fmaf(w, rk, ak[j]);
        av[j] = fmaf(w, rv, av[j]);
      }
    }
#pragma unroll
    for (int j = 0; j < 4; j++)
      if (nb + j < NN) {
        Qh[(size_t)(nb + j) * 64 + lane] = aq[j];
        Kh[(size_t)(nb + j) * 64 + lane] = ak[j];
        Vh[(size_t)(nb + j) * 64 + lane] = av[j];
      }
  }
}

// ---------------- CSR build ----------------
__global__ __launch_bounds__(256) void hist_kernel(const int* __restrict__ eidx, int* __restrict__ cnt) {
  int i = blockIdx.x * 256 + threadIdx.x;
  if (i < NE) atomicAdd(&cnt[eidx[NE + i]], 1);
}

__global__ __launch_bounds__(256) void scan_kernel(const int* __restrict__ cnt,
                                                   int* __restrict__ rs, int* __restrict__ cur) {
  __shared__ int wsum[4];
  __shared__ int woff[4];
  __shared__ int carry;
  const int t = threadIdx.x, lane = t & 63, w = t >> 6;
  if (t == 0) carry = 0;
  __syncthreads();
  for (int base = 0; base < NN; base += 256) {
    int v = (base + t < NN) ? cnt[base + t] : 0;
    int s = v;
#pragma unroll
    for (int off = 1; off < 64; off <<= 1) {
      int u = __shfl_up(s, off);
      if (lane >= off) s += u;
    }
    if (lane == 63) wsum[w] = s;
    __syncthreads();
    if (t == 0) {
      int a = carry;
      for (int i = 0; i < 4; i++) { woff[i] = a; a += wsum[i]; }
      carry = a;
    }
    __syncthreads();
    if (base + t < NN) {
      int e = woff[w] + s - v;
      rs[base + t] = e;
      cur[base + t] = e;
    }
    __syncthreads();
  }
  if (t == 0) rs[NN] = carry;
}

__global__ __launch_bounds__(256) void scatter_kernel(const int* __restrict__ eidx,
                                                      int* __restrict__ cur, int* __restrict__ eid) {
  int i = blockIdx.x * 256 + threadIdx.x;
  if (i < NE) {
    int p = atomicAdd(&cur[eidx[NE + i]], 1);
    eid[p] = i;
  }
}

// ---------------- Edge pass: Ee GEMV + signed-sqrt gate + logits ----------------
__global__ __launch_bounds__(256) void edge_kernel(
    const float* __restrict__ ea,
    const float* __restrict__ We, const float* __restrict__ be,
    const float* __restrict__ Aw,
    const float* __restrict__ Qh, const float* __restrict__ Kh,
    const int* __restrict__ eidx,
    bf16* __restrict__ sE, float* __restrict__ aE) {
  __shared__ float WeP[8192];  // permuted: col j<64 -> Ew lane order, j>=64 -> Eb lane order
  __shared__ float beP[128];
  __shared__ float awL[64];
  const int tid = threadIdx.x;
  for (int i = tid; i < 8192; i += 256) {
    int k = i >> 7, j = i & 127;
    int jj = j & 63;
    int col = 16 * (jj >> 3) + (jj & 7) + ((j >= 64) ? 8 : 0);
    WeP[i] = We[k * 128 + col];
  }
  if (tid < 128) {
    int jj = tid & 63;
    beP[tid] = be[16 * (jj >> 3) + (jj & 7) + ((tid >= 64) ? 8 : 0)];
  }
  if (tid < 64) awL[tid] = Aw[(tid & 7) * 8 + (tid >> 3)];  // Aw[c][h]
  __syncthreads();
  const int lane = tid & 63;
  const int gw = blockIdx.x * 4 + (tid >> 6);
  const int stride = gridDim.x * 4 * 4;
  for (int base = gw * 4; base < NE; base += stride) {
    float ear[4] = {0.f, 0.f, 0.f, 0.f};
#pragma unroll
    for (int j = 0; j < 4; j++)
      if (base + j < NE) ear[j] = ea[(size_t)(base + j) * 64 + lane];
    float accw[4], accb[4];
#pragma unroll
    for (int j = 0; j < 4; j++) { accw[j] = beP[lane]; accb[j] = beP[64 + lane]; }
#pragma unroll
    for (int k = 0; k < 64; k++) {
      float cw = WeP[k * 128 + lane];
      float cb = WeP[k * 128 + 64 + lane];
#pragma unroll
      for (int j = 0; j < 4; j++) {
        float w = __shfl(ear[j], k);
        accw[j] = fmaf(w, cw, accw[j]);
        accb[j] = fmaf(w, cb, accb[j]);
      }
    }
#pragma unroll
    for (int j = 0; j < 4; j++) {
      int e = base + j;
      if (e < NE) {
        int srcn = eidx[e];
        int dstn = eidx[NE + e];
        float s = (Kh[(size_t)srcn * 64 + lane] + Qh[(size_t)dstn * 64 + lane]) * accw[j];
        s = sqrtf(fmaxf(s, 0.f) + 1e-8f) - sqrtf(fmaxf(-s, 0.f) + 1e-8f);
        s += accb[j];
        sE[(size_t)e * 64 + lane] = __float2bfloat16(s);
        float p = s * awL[lane];
        p += __shfl_xor(p, 1);
        p += __shfl_xor(p, 2);
        p += __shfl_xor(p, 4);
        p = fminf(fmaxf(p, -5.f), 5.f);
        if ((lane & 7) == 0) aE[(size_t)e * 8 + (lane >> 3)] = p;
      }
    }
  }
}

// ---------------- Node pass: softmax + aggregation + full node epilogue ----------------
__global__ __launch_bounds__(1024) void node_kernel(
    const float* __restrict__ x, const float* __restrict__ log_deg,
    const float* __restrict__ VeRow, const float* __restrict__ deg_coef,
    const float* __restrict__ Woh, const float* __restrict__ boh,
    const float* __restrict__ g1, const float* __restrict__ bb1,
    const float* __restrict__ W1, const float* __restrict__ b1,
    const float* __restrict__ W2, const float* __restrict__ b2,
    const float* __restrict__ g2, const float* __restrict__ bb2,
    const float* __restrict__ Vh, const bf16* __restrict__ sE, const float* __restrict__ aE,
    const int* __restrict__ eidx, const int* __restrict__ rs, const int* __restrict__ eid,
    float* __restrict__ out) {
  extern __shared__ float sm[];
  float* WohL = sm;            // 4096
  float* W1L = sm + 4096;      // 8192
  float* W2L = sm + 12288;     // 8192
  float* VeL = sm + 20480;     // 512
  float* smallL = sm + 20992;  // 640
  const int tid = threadIdx.x;
  for (int i = tid; i < 4096; i += 1024) WohL[i] = Woh[i];
  for (int i = tid; i < 8192; i += 1024) W1L[i] = W1[i];
  for (int i = tid; i < 8192; i += 1024) W2L[i] = W2[i];
  if (tid < 512) VeL[tid] = VeRow[tid];
  if (tid < 64) smallL[tid] = boh[tid];
  if (tid < 128) smallL[64 + tid] = b1[tid];
  if (tid < 64) smallL[192 + tid] = b2[tid];
  if (tid < 64) smallL[256 + tid] = g1[tid];
  if (tid < 64) smallL[320 + tid] = bb1[tid];
  if (tid < 64) smallL[384 + tid] = g2[tid];
  if (tid < 64) smallL[448 + tid] = bb2[tid];
  if (tid < 128) smallL[512 + tid] = deg_coef[tid];
  __syncthreads();
  const float* bohL = smallL;
  const float* b1L = smallL + 64;
  const float* b2L = smallL + 192;
  const float* g1L = smallL + 256;
  const float* b1hL = smallL + 320;
  const float* g2L = smallL + 384;
  const float* b2hL = smallL + 448;
  const float* dcL = smallL + 512;
  const int lane = tid & 63;
  const int h = lane >> 3;
  const int gw = blockIdx.x * 16 + (tid >> 6);
  const int stride = gridDim.x * 16;
  for (int n = gw; n < NN; n += stride) {
    const int beg = rs[n], end = rs[n + 1];
    float den = 0.f;
    for (int i = beg; i < end; i++) {
      int e = eid[i];
      den += expf(aE[(size_t)e * 8 + h]);
    }
    float inv = 1.f / (den + 1e-16f);
    float wv = 0.f, rv = 0.f;
    for (int i = beg; i < end; i++) {
      int e = eid[i];
      float attn = expf(aE[(size_t)e * 8 + h]) * inv;
      int srcn = eidx[e];
      wv = fmaf(Vh[(size_t)srcn * 64 + lane], attn, wv);
      rv = fmaf(__bfloat162float(sE[(size_t)e * 64 + lane]), attn, rv);
    }
    // wV += rowV @ VeRow  (per head)
#pragma unroll
    for (int d2 = 0; d2 < 8; d2++) {
      float r = __shfl(rv, (lane & 56) + d2);
      wv = fmaf(r, VeL[d2 * 64 + lane], wv);
    }
    float ld = log_deg[n];
    float hv = wv * (dcL[2 * lane] + ld * dcL[2 * lane + 1]);
    float acc = bohL[lane];
#pragma unroll
    for (int k = 0; k < 64; k++) acc = fmaf(__shfl(hv, k), WohL[k * 64 + lane], acc);
    float r1 = x[(size_t)n * 64 + lane] + acc;
    float m = wave_sum(r1) * 0.015625f;
    float dv = r1 - m;
    float var = wave_sum(dv * dv) * 0.015625f;
    float h1 = dv * rsqrtf(var + 1e-5f) * g1L[lane] + b1hL[lane];
    float ua = b1L[lane], ub = b1L[64 + lane];
#pragma unroll
    for (int k = 0; k < 64; k++) {
      float wk = __shfl(h1, k);
      ua = fmaf(wk, W1L[k * 128 + lane], ua);
      ub = fmaf(wk, W1L[k * 128 + 64 + lane], ub);
    }
    ua = fmaxf(ua, 0.f);
    ub = fmaxf(ub, 0.f);
    float a2 = b2L[lane];
#pragma unroll
    for (int k = 0; k < 64; k++) {
      a2 = fmaf(__shfl(ua, k), W2L[k * 64 + lane], a2);
      a2 = fmaf(__shfl(ub, k), W2L[(64 + k) * 64 + lane], a2);
    }
    float r2 = h1 + a2;
    m = wave_sum(r2) * 0.015625f;
    dv = r2 - m;
    var = wave_sum(dv * dv) * 0.015625f;
    out[(size_t)n * 64 + lane] = dv * rsqrtf(var + 1e-5f) * g2L[lane] + b2hL[lane];
  }
}

// ---------------- Edge output: e = LN(edge_attr + s @ Woe + boe) ----------------
__global__ __launch_bounds__(256) void eout_kernel(
    const float* __restrict__ ea, const bf16* __restrict__ sE,
    const float* __restrict__ Woe, const float* __restrict__ boe,
    const float* __restrict__ g, const float* __restrict__ b,
    float* __restrict__ out) {
  __shared__ float WL[4096];
  __shared__ float boL[64], gL[64], bL[64];
  const int tid = threadIdx.x;
  for (int i = tid; i < 4096; i += 256) WL[i] = Woe[i];
  if (tid < 64) { boL[tid] = boe[tid]; gL[tid] = g[tid]; bL[tid] = b[tid]; }
  __syncthreads();
  const int lane = tid & 63;
  const int gw = blockIdx.x * 4 + (tid >> 6);
  const int stride = gridDim.x * 4 * 4;
  for (int base = gw * 4; base < NE; base += stride) {
    float sv[4] = {0.f, 0.f, 0.f, 0.f};
#pragma unroll
    for (int j = 0; j < 4; j++)
      if (base + j < NE) sv[j] = __bfloat162float(sE[(size_t)(base + j) * 64 + lane]);
    float acc[4];
#pragma unroll
    for (int j = 0; j < 4; j++) acc[j] = boL[lane];
#pragma unroll
    for (int k = 0; k < 64; k++) {
      float r = WL[k * 64 + lane];
#pragma unroll
      for (int j = 0; j < 4; j++) acc[j] = fmaf(__shfl(sv[j], k), r, acc[j]);
    }
#pragma unroll
    for (int j = 0; j < 4; j++) {
      int e = base + j;
      if (e < NE) {
        float r1 = ea[(size_t)e * 64 + lane] + acc[j];
        float m = wave_sum(r1) * 0.015625f;
        float dv = r1 - m;
        float var = wave_sum(dv * dv) * 0.015625f;
        out[(size_t)e * 64 + lane] = dv * rsqrtf(var + 1e-5f) * gL[lane] + bL[lane];
      }
    }
  }
}

extern "C" void kernel_launch(void* const* d_in, const int* in_sizes, int n_in,
                              void* d_out, int out_size, void* d_ws, size_t ws_size,
                              hipStream_t stream) {
  const float* x = (const float*)d_in[0];
  const float* ea = (const float*)d_in[1];
  const float* log_deg = (const float*)d_in[2];
  const float* Wq = (const float*)d_in[3];
  const float* bq = (const float*)d_in[4];
  const float* Wk = (const float*)d_in[5];
  const float* bk = (const float*)d_in[6];
  const float* Wv = (const float*)d_in[7];
  const float* bv = (const float*)d_in[8];
  const float* We = (const float*)d_in[9];
  const float* be = (const float*)d_in[10];
  const float* Aw = (const float*)d_in[11];
  const float* VeRow = (const float*)d_in[12];
  const float* deg_coef = (const float*)d_in[13];
  const float* Woh = (const float*)d_in[14];
  const float* boh = (const float*)d_in[15];
  const float* Woe = (const float*)d_in[16];
  const float* boe = (const float*)d_in[17];
  const float* g1h = (const float*)d_in[18];
  const float* b1h = (const float*)d_in[19];
  const float* g1e = (const float*)d_in[20];
  const float* b1e = (const float*)d_in[21];
  const float* W1 = (const float*)d_in[22];
  const float* b1 = (const float*)d_in[23];
  const float* W2 = (const float*)d_in[24];
  const float* b2 = (const float*)d_in[25];
  const float* g2h = (const float*)d_in[26];
  const float* b2h = (const float*)d_in[27];
  const int* eidx = (const int*)d_in[28];

  char* p = (char*)d_ws;
  float* Qh = (float*)p; p += (size_t)NN * 64 * 4;
  float* Kh = (float*)p; p += (size_t)NN * 64 * 4;
  float* Vh = (float*)p; p += (size_t)NN * 64 * 4;
  bf16* sE = (bf16*)p;  p += (size_t)NE * 64 * 2;
  float* aE = (float*)p; p += (size_t)NE * 8 * 4;
  int* cnt = (int*)p;   p += ((size_t)NN * 4 + 255) & ~(size_t)255;
  int* rs = (int*)p;    p += (((size_t)NN + 1) * 4 + 255) & ~(size_t)255;
  int* cur = (int*)p;   p += ((size_t)NN * 4 + 255) & ~(size_t)255;
  int* eid = (int*)p;   p += (size_t)NE * 4;
  if ((size_t)(p - (char*)d_ws) > ws_size) return;  // workspace too small; fail loudly

  float* out_h = (float*)d_out;
  float* out_e = out_h + (size_t)NN * 64;

  hipMemsetAsync(cnt, 0, NN * sizeof(int), stream);
  qkv_kernel<<<512, 256, 0, stream>>>(x, Wq, bq, Wk, bk, Wv, bv, Qh, Kh, Vh);
  hist_kernel<<<(NE + 255) / 256, 256, 0, stream>>>(eidx, cnt);
  scan_kernel<<<1, 256, 0, stream>>>(cnt, rs, cur);
  scatter_kernel<<<(NE + 255) / 256, 256, 0, stream>>>(eidx, cur, eid);
  edge_kernel<<<2048, 256, 0, stream>>>(ea, We, be, Aw, Qh, Kh, eidx, sE, aE);
  node_kernel<<<512, 1024, 21632 * 4, stream>>>(x, log_deg, VeRow, deg_coef, Woh, boh,
                                                g1h, b1h, W1, b1, W2, b2, g2h, b2h,
                                                Vh, sE, aE, eidx, rs, eid, out_h);
  eout_kernel<<<2048, 256, 0, stream>>>(ea, sE, Woe, boe, g1e, b1e, out_e);
}